// Round 3
// baseline (88.270 us; speedup 1.0000x reference)
//
#include <hip/hip_runtime.h>

// SVF cascade frequency response on MI355X (gfx950) — R14.
//
// H(x) = (1+1j) * prod_k (b0*x^2+b1*x+b2)/(a0*x^2+a1*x+a2)
//
// Established: PLANAR output [Re H | Im H]; per-stage division (never
// reopen deferred — full-product dens overflow f32); coef delivery via
// d_ws; all stores guarded; pow2 per-stage normalization (ratio-exact).
//
// R14: OCCUPANCY, not op count. R13's −11% op cut (hexadecic) moved dur
// by ~0 -> main kernel is latency/stall-bound, not issue-bound (runs at
// ~4.4x the ~9.3 µs VALU issue floor). R11/R13 sat in the 65-128 VGPR
// band = 4 waves/SIMD (occupancy halves at 64/128/256); identical waves
// stall in lockstep on per-stage coef waits + serial division tails.
// Fix: shrink live state so the kernel fits <=64 VGPR and force
// __launch_bounds__(256,8) -> 8 waves/SIMD (2x TLP to de-correlate
// stalls). That requires octic stages (8 powers = 16 regs) at MPT=1
// (~35-45 VGPR live): +12% ops vs hexadecic, but ops are proven-cheap.
// Coefs: 16 stages x 18 f32 = 1152 B in d_ws, f64 build, pow2-normalized.

#define NSEC  64
#define NOCT  16    // stages (4 fused biquads each)
#define DEG   8     // polynomial degree per stage
#define NCF   18    // 9 num + 9 den coefficients per stage
#define BLOCK 256

// Pre-kernel: octic coefficients in f64, normalized, stored f32.
// Layout (ascending powers): coef[t*18 + j]     = num coeff of x^j
//                            coef[t*18 + 9 + j] = den coeff of x^j
__global__ __launch_bounds__(64) void svf_coef_v14(
    const float* __restrict__ f_g,  const float* __restrict__ R_g,
    const float* __restrict__ lp_g, const float* __restrict__ bp_g,
    const float* __restrict__ hp_g,
    float* __restrict__ coef)
{
    const int t = threadIdx.x;
    if (t >= NOCT) return;

    double pn[DEG + 1], pd[DEG + 1];
    #pragma unroll
    for (int j = 0; j <= DEG; ++j) { pn[j] = 0.0; pd[j] = 0.0; }
    pn[0] = 1.0; pd[0] = 1.0;

    // Sequentially convolve 4 biquads (ascending-power convention:
    // num*x^2 = b2 + b1*x + b0*x^2, den*x^2 = a2 + a1*x + a0*x^2).
    #pragma unroll
    for (int s = 0; s < 4; ++s) {
        const int k = 4 * t + s;
        const double fk = (double)f_g[k],  Rk = (double)R_g[k];
        const double lp = (double)lp_g[k], bp = (double)bp_g[k], hp = (double)hp_g[k];
        const double f2 = fk * fk, fbp = fk * bp, flp = f2 * lp, rf2 = 2.0 * Rk * fk;
        const double bb0 = flp - fbp + hp;          // x^0 term (= b2)
        const double bb1 = 2.0 * flp - 2.0 * hp;    // x^1 term (= b1)
        const double bb2 = flp + fbp + hp;          // x^2 term (= b0)
        const double aa0 = f2 - rf2 + 1.0;
        const double aa1 = 2.0 * f2 - 2.0;
        const double aa2 = f2 + rf2 + 1.0;

        double nn[DEG + 1], nd[DEG + 1];
        #pragma unroll
        for (int j = 0; j <= DEG; ++j) { nn[j] = 0.0; nd[j] = 0.0; }
        #pragma unroll
        for (int i = 0; i <= DEG - 2; ++i) {   // pn[i]=0 beyond current deg
            nn[i]     += pn[i] * bb0;
            nn[i + 1] += pn[i] * bb1;
            nn[i + 2] += pn[i] * bb2;
            nd[i]     += pd[i] * aa0;
            nd[i + 1] += pd[i] * aa1;
            nd[i + 2] += pd[i] * aa2;
        }
        #pragma unroll
        for (int j = 0; j <= DEG; ++j) { pn[j] = nn[j]; pd[j] = nd[j]; }
    }

    // Power-of-2 normalization: same factor on num and den -> ratio is
    // EXACTLY preserved; keeps f32 eval and |den|^2 far from range edges.
    double mx = 0.0;
    #pragma unroll
    for (int j = 0; j <= DEG; ++j) mx = fmax(mx, fabs(pd[j]));
    const double sc = (mx > 0.0) ? ldexp(1.0, -ilogb(mx)) : 1.0;

    float* cp = coef + t * NCF;
    #pragma unroll
    for (int j = 0; j <= DEG; ++j) {
        cp[j]           = (float)(pn[j] * sc);
        cp[DEG + 1 + j] = (float)(pd[j] * sc);
    }
}

// complex square / multiply helpers (fma-contracted)
#define CSQ(dr_, di_, ar_, ai_)                                   \
    dr_ = fmaf((ar_), (ar_), -((ai_) * (ai_)));                   \
    di_ = 2.0f * ((ar_) * (ai_));
#define CMUL(dr_, di_, ar_, ai_, br_, bi_)                        \
    dr_ = fmaf((ar_), (br_), -((ai_) * (bi_)));                   \
    di_ = fmaf((ar_), (bi_),  ((ai_) * (br_)));

// MPT=1, live state ~35-45 VGPR -> <=64 VGPR -> 8 waves/SIMD.
__global__ __launch_bounds__(BLOCK, 8) void svf_f32_v14(
    const float* __restrict__ xr_g, const float* __restrict__ xi_g,
    const float* __restrict__ coef,
    float* __restrict__ out, int n, long long cap_floats)
{
    const long long idx = (long long)blockIdx.x * BLOCK + threadIdx.x;
    const bool ok = idx < (long long)n;

    const float x1r = ok ? xr_g[idx] : 1.0f;
    const float x1i = ok ? xi_g[idx] : 0.0f;

    // powers x^1..x^8 (Xr[q-1], Xi[q-1] hold x^q); static indexing only.
    float Xr[8], Xi[8];
    Xr[0] = x1r; Xi[0] = x1i;
    CSQ (Xr[1], Xi[1], Xr[0], Xi[0]);                     // x^2
    CMUL(Xr[2], Xi[2], Xr[1], Xi[1], Xr[0], Xi[0]);       // x^3
    CSQ (Xr[3], Xi[3], Xr[1], Xi[1]);                     // x^4
    CMUL(Xr[4], Xi[4], Xr[3], Xi[3], Xr[0], Xi[0]);       // x^5
    CSQ (Xr[5], Xi[5], Xr[2], Xi[2]);                     // x^6
    CMUL(Xr[6], Xi[6], Xr[3], Xi[3], Xr[2], Xi[2]);       // x^7
    CSQ (Xr[7], Xi[7], Xr[3], Xi[3]);                     // x^8

    float Hr = 1.0f, Hi = 1.0f;   // H starts at (1 + 1j)

    #pragma unroll
    for (int p = 0; p < NOCT; ++p) {
        // Loop-uniform -> s_load; full unroll pipelines coef loads
        // across stages.
        const float* cp = coef + p * NCF;
        float cn[9], cd[9];
        #pragma unroll
        for (int j = 0; j < 9; ++j) { cn[j] = cp[j]; cd[j] = cp[9 + j]; }

        // num/den octic: real coefs (ascending) dotted against complex
        // powers — 4 independent 8-fma chains.
        float nr = cn[0], ni = 0.0f, dr = cd[0], di = 0.0f;
        #pragma unroll
        for (int q = 1; q <= 8; ++q) {
            nr = fmaf(cn[q], Xr[q - 1], nr);
            ni = fmaf(cn[q], Xi[q - 1], ni);
            dr = fmaf(cd[q], Xr[q - 1], dr);
            di = fmaf(cd[q], Xi[q - 1], di);
        }
        // ratio = num * conj(den) / |den|^2 (per-stage division)
        const float dd  = fmaf(dr, dr, di * di);
        const float inv = __builtin_amdgcn_rcpf(dd);   // ~1e-7 rel x 16, ok
        const float tr  = fmaf(nr, dr,   ni * di);
        const float ti  = fmaf(ni, dr, -(nr * di));
        const float rr  = tr * inv;
        const float ri  = ti * inv;
        // H *= ratio
        const float hr = fmaf(Hr, rr, -(Hi * ri));
        const float hi = fmaf(Hr, ri,   Hi * rr);
        Hr = hr; Hi = hi;
    }

    // PLANAR output: out[0..n-1] = Re H, out[n..2n-1] = Im H. Guarded.
    if (ok) {
        if (idx + 1 <= cap_floats) out[idx] = Hr;
        const long long oi = (long long)n + idx;
        if (oi + 1 <= cap_floats) out[oi] = Hi;
    }
}

extern "C" void kernel_launch(void* const* d_in, const int* in_sizes, int n_in,
                              void* d_out, int out_size, void* d_ws, size_t ws_size,
                              hipStream_t stream) {
    const float* xr = (const float*)d_in[0];
    const float* xi = (const float*)d_in[1];
    const float* f  = (const float*)d_in[2];
    const float* R  = (const float*)d_in[3];
    const float* lp = (const float*)d_in[4];
    const float* bp = (const float*)d_in[5];
    const float* hp = (const float*)d_in[6];
    float* out = (float*)d_out;
    float* coef = (float*)d_ws;   // 16*18*4 = 1152 B of scratch

    const int n = in_sizes[0];  // 1048576
    long long cap = (long long)out_size;
    if (cap > 2LL * (long long)n) cap = 2LL * (long long)n;

    // Stage 1: octic coefficients (f64 math, pow2-normalized, f32 store).
    svf_coef_v14<<<1, 64, 0, stream>>>(f, R, lp, bp, hp, coef);
    // Stage 2: main sweep, all-f32, 16 fully-unrolled octic stages,
    // MPT=1, <=64 VGPR target -> 8 waves/SIMD.
    const int grid = (n + BLOCK - 1) / BLOCK;  // 4096
    svf_f32_v14<<<grid, BLOCK, 0, stream>>>(xr, xi, coef, out, n, cap);
}